// Round 1
// 442.910 us; speedup vs baseline: 1.0243x; 1.0243x over previous
//
#include <hip/hip_runtime.h>
#include <hip/hip_bf16.h>

#define NTOT 8192
#define DDIM 256
#define ROWS 32                 // rows per attn block
#define JCHUNK (NTOT / 8)       // 1024 j per wave (8 waves j-split in block)
#define NITER (JCHUNK / 32)     // 32 K-tiles per wave
#define NTSTR 131584            // hTf nt-stride in elems: 257*64*8 (+1KB/256KB, breaks L2 channel aliasing)

typedef __attribute__((ext_vector_type(8))) short short8;
typedef __attribute__((ext_vector_type(4))) float floatx4;
typedef __attribute__((ext_vector_type(4))) int intx4;

// ------- per-row exp tables: rc=(e^s1, e^.01s1), etab=(e^s2, e^.01s2)
// leaky-exp select is a max: exp(leaky(s1+s2)) = max(e^s1*e^s2, e^.01s1*e^.01s2)
__global__ __launch_bounds__(256) void gat_scores(const float* __restrict__ h,
                                                  const float* __restrict__ a,
                                                  float4* __restrict__ rc,
                                                  float2* __restrict__ etab) {
  int row  = blockIdx.x * 4 + (threadIdx.x >> 6);
  int lane = threadIdx.x & 63;
  const float* hr = h + (size_t)row * DDIM;
  float p1 = 0.f, p2 = 0.f;
#pragma unroll
  for (int k = 0; k < DDIM / 64; ++k) {
    int idx  = lane + 64 * k;
    float hv = hr[idx];
    p1 += hv * a[idx];
    p2 += hv * a[DDIM + idx];
  }
#pragma unroll
  for (int off = 32; off > 0; off >>= 1) {
    p1 += __shfl_down(p1, off, 64);
    p2 += __shfl_down(p2, off, 64);
  }
  if (lane == 0) {
    rc[row]   = make_float4(__expf(p1), __expf(0.01f * p1), 0.f, 0.f);
    etab[row] = make_float2(__expf(p2), __expf(0.01f * p2));
  }
}

// ---------------- pack h -> fragment-major bf16 hTf (padded nt-stride) ------
// hTf[((n*257 + jblk)*64 + lane)*8 + i] = H[jblk*32 + (lane>>4)*8 + i][n*16 + (lane&15)]
__global__ __launch_bounds__(256) void gat_hpack(const float* __restrict__ h,
                                                 ushort* __restrict__ hTf) {
  __shared__ float tile[64][257];
  const int t    = threadIdx.x;
  const int lane = t & 63;
  const int w    = t >> 6;
  const int quad = lane >> 4;
  const int c    = lane & 15;
  const int i0   = blockIdx.x * 64;

#pragma unroll
  for (int it = 0; it < 16; ++it) {
    int r = it * 4 + w;
    float4 v = *(const float4*)(h + (size_t)(i0 + r) * DDIM + lane * 4);
    tile[r][lane * 4 + 0] = v.x; tile[r][lane * 4 + 1] = v.y;
    tile[r][lane * 4 + 2] = v.z; tile[r][lane * 4 + 3] = v.w;
  }
  __syncthreads();

#pragma unroll
  for (int k = 0; k < 4; ++k) {
    const int n = 4 * k + w;
#pragma unroll
    for (int jbl = 0; jbl < 2; ++jbl) {
      short8 vv;
#pragma unroll
      for (int i = 0; i < 8; ++i) {
        float f = tile[jbl * 32 + quad * 8 + i][n * 16 + c];
        __hip_bfloat16 b = __float2bfloat16(f);
        vv[i] = *(short*)&b;
      }
      *(short8*)(hTf + ((size_t)(n * 257 + i0 / 32 + jbl) * 64 + lane) * 8) = vv;
    }
  }
}

// ---------------- barrier-free fused softmax + P@h via MFMA -----------------
// 256 blocks x 512 thr. Block rows [r0,r0+32); wave w: j in [1024w,1024w+1024).
// adj read DIRECTLY (pack kernel eliminated): lane (quad,c) prefetches
// adj[r0+c][jbase+quad*8 .. +8] and adj[r0+16+c][...] as int4 pairs, one
// iteration ahead (issued where the old bitmask words were prefetched).
__global__ __launch_bounds__(512, 2) void gat_attn(const ushort* __restrict__ hTf,
                                                   const int* __restrict__ adj,
                                                   const float4* __restrict__ rc,
                                                   const float2* __restrict__ etab,
                                                   float* __restrict__ out) {
  __shared__ union {
    float lred[8][32];
    float slab[4][ROWS * 128];
  } sh;

  const int t    = threadIdx.x;
  const int lane = t & 63;
  const int w    = t >> 6;
  const int quad = lane >> 4;
  const int c    = lane & 15;
  const int r0   = blockIdx.x * ROWS;

  const float4 rc0 = rc[r0 + c];        // (E1, E2) for A-row frag 0
  const float4 rc1 = rc[r0 + 16 + c];   // for A-row frag 1
  const float E10 = rc0.x, E20 = rc0.y;
  const float E11 = rc1.x, E21 = rc1.y;

  const int* ap0 = adj + (size_t)(r0 + c) * NTOT + (size_t)w * JCHUNK + quad * 8;
  const int* ap1 = ap0 + (size_t)16 * NTOT;
  const float*    etb = (const float*)(etab + (size_t)w * JCHUNK + quad * 8);
  const ushort*   hfp = hTf + ((size_t)(w * 32) * 64 + lane) * 8;

  floatx4 acc[2][16];
#pragma unroll
  for (int rt = 0; rt < 2; ++rt)
#pragma unroll
    for (int nt = 0; nt < 16; ++nt) acc[rt][nt] = (floatx4){0.f, 0.f, 0.f, 0.f};

  float lp0 = 0.f, lp1 = 0.f;
  short8 bA[8], bB[8];

  // prologue: first half-0 B-frags + first adj/etab
  #define LDH(dst, jt, half)                                                   \
    _Pragma("unroll")                                                          \
    for (int q = 0; q < 8; ++q)                                                \
      dst[q] = *(const short8*)(hfp + (size_t)(jt) * 512 +                     \
                                (size_t)((half) * 8 + q) * NTSTR);

  LDH(bA, 0, 0)
  intx4 A0a = *(const intx4*)ap0;
  intx4 A0b = *(const intx4*)(ap0 + 4);
  intx4 A1a = *(const intx4*)ap1;
  intx4 A1b = *(const intx4*)(ap1 + 4);
  float4 ea = ((const float4*)etb)[0];
  float4 eb = ((const float4*)etb)[1];
  float4 ec = ((const float4*)etb)[2];
  float4 ed = ((const float4*)etb)[3];

  for (int jt = 0; jt < NITER; ++jt) {
    // ---- issue half-1 B-frag loads (land during P-build) ----
    LDH(bB, jt, 1)

    // ---- P-build: p = (adj>0) ? max(E1*t1, E2*t2) : 0 ----
    const int am0[8] = {A0a[0], A0a[1], A0a[2], A0a[3], A0b[0], A0b[1], A0b[2], A0b[3]};
    const int am1[8] = {A1a[0], A1a[1], A1a[2], A1a[3], A1b[0], A1b[1], A1b[2], A1b[3]};
    float tp[16] = {ea.x, ea.y, ea.z, ea.w, eb.x, eb.y, eb.z, eb.w,
                    ec.x, ec.y, ec.z, ec.w, ed.x, ed.y, ed.z, ed.w};
    short8 pa0, pa1;
#pragma unroll
    for (int i = 0; i < 8; ++i) {
      const float t1 = tp[2 * i], t2 = tp[2 * i + 1];
      float p0 = (am0[i] > 0) ? fmaxf(E10 * t1, E20 * t2) : 0.f;
      float p1 = (am1[i] > 0) ? fmaxf(E11 * t1, E21 * t2) : 0.f;
      lp0 += p0; lp1 += p1;
      __hip_bfloat16 b0 = __float2bfloat16(p0);
      __hip_bfloat16 b1 = __float2bfloat16(p1);
      pa0[i] = *(short*)&b0;
      pa1[i] = *(short*)&b1;
    }

    // ---- prefetch next body's adj + etab (hides HBM latency under MFMAs) ----
    if (jt + 1 < NITER) {
      const int* n0 = ap0 + (size_t)(jt + 1) * 32;
      A0a = *(const intx4*)n0;
      A0b = *(const intx4*)(n0 + 4);
      const int* n1 = ap1 + (size_t)(jt + 1) * 32;
      A1a = *(const intx4*)n1;
      A1b = *(const intx4*)(n1 + 4);
      const float* en = etb + (jt + 1) * 64;
      ea = ((const float4*)en)[0];
      eb = ((const float4*)en)[1];
      ec = ((const float4*)en)[2];
      ed = ((const float4*)en)[3];
    }

    // ---- MFMA half 0 (bA), then start next body's half-0 loads ----
#pragma unroll
    for (int q = 0; q < 8; ++q) {
      acc[0][q] = __builtin_amdgcn_mfma_f32_16x16x32_bf16(pa0, bA[q], acc[0][q], 0, 0, 0);
      acc[1][q] = __builtin_amdgcn_mfma_f32_16x16x32_bf16(pa1, bA[q], acc[1][q], 0, 0, 0);
    }
    if (jt + 1 < NITER) { LDH(bA, jt + 1, 0) }

    // ---- MFMA half 1 (bB) ----
#pragma unroll
    for (int q = 0; q < 8; ++q) {
      acc[0][8 + q] = __builtin_amdgcn_mfma_f32_16x16x32_bf16(pa0, bB[q], acc[0][8 + q], 0, 0, 0);
      acc[1][8 + q] = __builtin_amdgcn_mfma_f32_16x16x32_bf16(pa1, bB[q], acc[1][8 + q], 0, 0, 0);
    }
  }
  #undef LDH

  // ---- row-sum reduce: quads -> lanes 0-15, then LDS across waves ----
  lp0 += __shfl_xor(lp0, 16, 64); lp0 += __shfl_xor(lp0, 32, 64);
  lp1 += __shfl_xor(lp1, 16, 64); lp1 += __shfl_xor(lp1, 32, 64);
  if (quad == 0) { sh.lred[w][c] = lp0; sh.lred[w][16 + c] = lp1; }
  __syncthreads();

  float linv[2][4];
  if (w == 0) {
#pragma unroll
    for (int rt = 0; rt < 2; ++rt)
#pragma unroll
      for (int reg = 0; reg < 4; ++reg) {
        int lrow = rt * 16 + quad * 4 + reg;
        float s = 0.f;
#pragma unroll
        for (int wi = 0; wi < 8; ++wi) s += sh.lred[wi][lrow];
        linv[rt][reg] = 1.f / s;
      }
  }
  __syncthreads();

  // ---- log-depth acc reduction over 8 waves, per 128-col half ----
#pragma unroll
  for (int hd = 0; hd < 2; ++hd) {
    if (w >= 4) {
#pragma unroll
      for (int rt = 0; rt < 2; ++rt)
#pragma unroll
        for (int i = 0; i < 8; ++i)
#pragma unroll
          for (int reg = 0; reg < 4; ++reg)
            sh.slab[w - 4][(rt * 16 + quad * 4 + reg) * 128 + i * 16 + c] =
                acc[rt][i + 8 * hd][reg];
    }
    __syncthreads();
    if (w < 4) {
#pragma unroll
      for (int rt = 0; rt < 2; ++rt)
#pragma unroll
        for (int i = 0; i < 8; ++i)
#pragma unroll
          for (int reg = 0; reg < 4; ++reg)
            acc[rt][i + 8 * hd][reg] +=
                sh.slab[w][(rt * 16 + quad * 4 + reg) * 128 + i * 16 + c];
    }
    __syncthreads();
    if (w == 2 || w == 3) {
#pragma unroll
      for (int rt = 0; rt < 2; ++rt)
#pragma unroll
        for (int i = 0; i < 8; ++i)
#pragma unroll
          for (int reg = 0; reg < 4; ++reg)
            sh.slab[w - 2][(rt * 16 + quad * 4 + reg) * 128 + i * 16 + c] =
                acc[rt][i + 8 * hd][reg];
    }
    __syncthreads();
    if (w < 2) {
#pragma unroll
      for (int rt = 0; rt < 2; ++rt)
#pragma unroll
        for (int i = 0; i < 8; ++i)
#pragma unroll
          for (int reg = 0; reg < 4; ++reg)
            acc[rt][i + 8 * hd][reg] +=
                sh.slab[w][(rt * 16 + quad * 4 + reg) * 128 + i * 16 + c];
    }
    __syncthreads();
    if (w == 1) {
#pragma unroll
      for (int rt = 0; rt < 2; ++rt)
#pragma unroll
        for (int i = 0; i < 8; ++i)
#pragma unroll
          for (int reg = 0; reg < 4; ++reg)
            sh.slab[0][(rt * 16 + quad * 4 + reg) * 128 + i * 16 + c] =
                acc[rt][i + 8 * hd][reg];
    }
    __syncthreads();
    if (w == 0) {
#pragma unroll
      for (int rt = 0; rt < 2; ++rt)
#pragma unroll
        for (int i = 0; i < 8; ++i)
#pragma unroll
          for (int reg = 0; reg < 4; ++reg) {
            float v = acc[rt][i + 8 * hd][reg] +
                      sh.slab[0][(rt * 16 + quad * 4 + reg) * 128 + i * 16 + c];
            out[(size_t)(r0 + rt * 16 + quad * 4 + reg) * DDIM +
                hd * 128 + i * 16 + c] = v * linv[rt][reg];
          }
    }
    __syncthreads();
  }
}

extern "C" void kernel_launch(void* const* d_in, const int* in_sizes, int n_in,
                              void* d_out, int out_size, void* d_ws, size_t ws_size,
                              hipStream_t stream) {
  const float* h   = (const float*)d_in[0];
  const int*   adj = (const int*)d_in[1];
  const float* a   = (const float*)d_in[2];
  float* out = (float*)d_out;

  float4*   rc    = (float4*)d_ws;                       // 8192 float4 = 128 KB
  float2*   etab  = (float2*)(rc + NTOT);                // 8192 float2 = 64 KB
  ushort*   hTf   = (ushort*)(etab + NTOT);              // ~4.21 MB bf16 (16B-aligned at 192KB)

  gat_scores<<<NTOT / 4, 256, 0, stream>>>(h, a, rc, etab);
  gat_hpack<<<NTOT / 64, 256, 0, stream>>>(h, hTf);
  gat_attn<<<NTOT / ROWS, 512, 0, stream>>>(hTf, adj, rc, etab, out);
}

// Round 2
// 425.674 us; speedup vs baseline: 1.0658x; 1.0405x over previous
//
#include <hip/hip_runtime.h>
#include <hip/hip_bf16.h>

#define NTOT 8192
#define DDIM 256
#define ROWS 32                 // rows per attn block
#define JCHUNK (NTOT / 8)       // 1024 j per wave (8 waves j-split in block)
#define NITER (JCHUNK / 32)     // 32 K-tiles per wave
#define NTSTR 131584            // hTf nt-stride in elems: 257*64*8 (+1KB/256KB, breaks L2 channel aliasing)

typedef __attribute__((ext_vector_type(8))) short short8;
typedef __attribute__((ext_vector_type(4))) float floatx4;
typedef __attribute__((ext_vector_type(4))) int intx4;

// ------- per-row exp tables: rc=(e^s1, e^.01s1), etab=(e^s2, e^.01s2)
// leaky-exp select is a max: exp(leaky(s1+s2)) = max(e^s1*e^s2, e^.01s1*e^.01s2)
__global__ __launch_bounds__(256) void gat_scores(const float* __restrict__ h,
                                                  const float* __restrict__ a,
                                                  float4* __restrict__ rc,
                                                  float2* __restrict__ etab) {
  int row  = blockIdx.x * 4 + (threadIdx.x >> 6);
  int lane = threadIdx.x & 63;
  const float* hr = h + (size_t)row * DDIM;
  float p1 = 0.f, p2 = 0.f;
#pragma unroll
  for (int k = 0; k < DDIM / 64; ++k) {
    int idx  = lane + 64 * k;
    float hv = hr[idx];
    p1 += hv * a[idx];
    p2 += hv * a[DDIM + idx];
  }
#pragma unroll
  for (int off = 32; off > 0; off >>= 1) {
    p1 += __shfl_down(p1, off, 64);
    p2 += __shfl_down(p2, off, 64);
  }
  if (lane == 0) {
    rc[row]   = make_float4(__expf(p1), __expf(0.01f * p1), 0.f, 0.f);
    etab[row] = make_float2(__expf(p2), __expf(0.01f * p2));
  }
}

// ---------------- pack h -> fragment-major bf16 hTf (padded nt-stride) ------
// hTf[((n*257 + jblk)*64 + lane)*8 + i] = H[jblk*32 + (lane>>4)*8 + i][n*16 + (lane&15)]
__global__ __launch_bounds__(256) void gat_hpack(const float* __restrict__ h,
                                                 ushort* __restrict__ hTf) {
  __shared__ float tile[64][257];
  const int t    = threadIdx.x;
  const int lane = t & 63;
  const int w    = t >> 6;
  const int quad = lane >> 4;
  const int c    = lane & 15;
  const int i0   = blockIdx.x * 64;

#pragma unroll
  for (int it = 0; it < 16; ++it) {
    int r = it * 4 + w;
    float4 v = *(const float4*)(h + (size_t)(i0 + r) * DDIM + lane * 4);
    tile[r][lane * 4 + 0] = v.x; tile[r][lane * 4 + 1] = v.y;
    tile[r][lane * 4 + 2] = v.z; tile[r][lane * 4 + 3] = v.w;
  }
  __syncthreads();

#pragma unroll
  for (int k = 0; k < 4; ++k) {
    const int n = 4 * k + w;
#pragma unroll
    for (int jbl = 0; jbl < 2; ++jbl) {
      short8 vv;
#pragma unroll
      for (int i = 0; i < 8; ++i) {
        float f = tile[jbl * 32 + quad * 8 + i][n * 16 + c];
        __hip_bfloat16 b = __float2bfloat16(f);
        vv[i] = *(short*)&b;
      }
      *(short8*)(hTf + ((size_t)(n * 257 + i0 / 32 + jbl) * 64 + lane) * 8) = vv;
    }
  }
}

// ---------------- barrier-free fused softmax + P@h via MFMA -----------------
// 256 blocks x 512 thr. Block rows [r0,r0+32); wave w: j in [1024w,1024w+1024).
// adj read directly with NON-TEMPORAL loads (read-once; keeps hTf hot in L2).
// Loop body is branch-free: prefetch index wraps (&31) so the last iteration
// issues a redundant-but-valid prefetch instead of a guarded one.
__global__ __launch_bounds__(512, 2) void gat_attn(const ushort* __restrict__ hTf,
                                                   const int* __restrict__ adj,
                                                   const float4* __restrict__ rc,
                                                   const float2* __restrict__ etab,
                                                   float* __restrict__ out) {
  __shared__ union {
    float lred[8][32];
    float slab[4][ROWS * 128];
  } sh;

  const int t    = threadIdx.x;
  const int lane = t & 63;
  const int w    = t >> 6;
  const int quad = lane >> 4;
  const int c    = lane & 15;
  const int r0   = blockIdx.x * ROWS;

  const float4 rc0 = rc[r0 + c];        // (E1, E2) for A-row frag 0
  const float4 rc1 = rc[r0 + 16 + c];   // for A-row frag 1
  const float E10 = rc0.x, E20 = rc0.y;
  const float E11 = rc1.x, E21 = rc1.y;

  const int* ap0 = adj + (size_t)(r0 + c) * NTOT + (size_t)w * JCHUNK + quad * 8;
  const int* ap1 = ap0 + (size_t)16 * NTOT;
  const float*    etb = (const float*)(etab + (size_t)w * JCHUNK + quad * 8);
  const ushort*   hfp = hTf + ((size_t)(w * 32) * 64 + lane) * 8;

  floatx4 acc[2][16];
#pragma unroll
  for (int rt = 0; rt < 2; ++rt)
#pragma unroll
    for (int nt = 0; nt < 16; ++nt) acc[rt][nt] = (floatx4){0.f, 0.f, 0.f, 0.f};

  float lp0 = 0.f, lp1 = 0.f;
  short8 bA[8], bB[8];

  // prologue: first half-0 B-frags + first adj/etab
  #define LDH(dst, jt, half)                                                   \
    _Pragma("unroll")                                                          \
    for (int q = 0; q < 8; ++q)                                                \
      dst[q] = *(const short8*)(hfp + (size_t)(jt) * 512 +                     \
                                (size_t)((half) * 8 + q) * NTSTR);

  LDH(bA, 0, 0)
  intx4 A0a = __builtin_nontemporal_load((const intx4*)ap0);
  intx4 A0b = __builtin_nontemporal_load((const intx4*)(ap0 + 4));
  intx4 A1a = __builtin_nontemporal_load((const intx4*)ap1);
  intx4 A1b = __builtin_nontemporal_load((const intx4*)(ap1 + 4));
  float4 ea = ((const float4*)etb)[0];
  float4 eb = ((const float4*)etb)[1];
  float4 ec = ((const float4*)etb)[2];
  float4 ed = ((const float4*)etb)[3];

  for (int jt = 0; jt < NITER; ++jt) {
    const int jn = (jt + 1) & (NITER - 1);   // wrapped prefetch index (branch-free)

    // ---- issue half-1 B-frag loads (land during P-build) ----
    LDH(bB, jt, 1)

    // ---- P-build: p = (adj>0) ? max(E1*t1, E2*t2) : 0 ----
    const int am0[8] = {A0a[0], A0a[1], A0a[2], A0a[3], A0b[0], A0b[1], A0b[2], A0b[3]};
    const int am1[8] = {A1a[0], A1a[1], A1a[2], A1a[3], A1b[0], A1b[1], A1b[2], A1b[3]};
    float tp[16] = {ea.x, ea.y, ea.z, ea.w, eb.x, eb.y, eb.z, eb.w,
                    ec.x, ec.y, ec.z, ec.w, ed.x, ed.y, ed.z, ed.w};
    short8 pa0, pa1;
#pragma unroll
    for (int i = 0; i < 8; ++i) {
      const float t1 = tp[2 * i], t2 = tp[2 * i + 1];
      float p0 = (am0[i] > 0) ? fmaxf(E10 * t1, E20 * t2) : 0.f;
      float p1 = (am1[i] > 0) ? fmaxf(E11 * t1, E21 * t2) : 0.f;
      lp0 += p0; lp1 += p1;
      __hip_bfloat16 b0 = __float2bfloat16(p0);
      __hip_bfloat16 b1 = __float2bfloat16(p1);
      pa0[i] = *(short*)&b0;
      pa1[i] = *(short*)&b1;
    }

    // ---- prefetch next body's adj + etab (unconditional, wrapped) ----
    {
      const int* n0 = ap0 + (size_t)jn * 32;
      A0a = __builtin_nontemporal_load((const intx4*)n0);
      A0b = __builtin_nontemporal_load((const intx4*)(n0 + 4));
      const int* n1 = ap1 + (size_t)jn * 32;
      A1a = __builtin_nontemporal_load((const intx4*)n1);
      A1b = __builtin_nontemporal_load((const intx4*)(n1 + 4));
      const float* en = etb + (size_t)jn * 64;
      ea = ((const float4*)en)[0];
      eb = ((const float4*)en)[1];
      ec = ((const float4*)en)[2];
      ed = ((const float4*)en)[3];
    }

    // ---- MFMA half 0 (bA), then start next body's half-0 loads ----
#pragma unroll
    for (int q = 0; q < 8; ++q) {
      acc[0][q] = __builtin_amdgcn_mfma_f32_16x16x32_bf16(pa0, bA[q], acc[0][q], 0, 0, 0);
      acc[1][q] = __builtin_amdgcn_mfma_f32_16x16x32_bf16(pa1, bA[q], acc[1][q], 0, 0, 0);
    }
    LDH(bA, jn, 0)

    // ---- MFMA half 1 (bB) ----
#pragma unroll
    for (int q = 0; q < 8; ++q) {
      acc[0][8 + q] = __builtin_amdgcn_mfma_f32_16x16x32_bf16(pa0, bB[q], acc[0][8 + q], 0, 0, 0);
      acc[1][8 + q] = __builtin_amdgcn_mfma_f32_16x16x32_bf16(pa1, bB[q], acc[1][8 + q], 0, 0, 0);
    }
  }
  #undef LDH

  // ---- row-sum reduce: quads -> lanes 0-15, then LDS across waves ----
  lp0 += __shfl_xor(lp0, 16, 64); lp0 += __shfl_xor(lp0, 32, 64);
  lp1 += __shfl_xor(lp1, 16, 64); lp1 += __shfl_xor(lp1, 32, 64);
  if (quad == 0) { sh.lred[w][c] = lp0; sh.lred[w][16 + c] = lp1; }
  __syncthreads();

  float linv[2][4];
  if (w == 0) {
#pragma unroll
    for (int rt = 0; rt < 2; ++rt)
#pragma unroll
      for (int reg = 0; reg < 4; ++reg) {
        int lrow = rt * 16 + quad * 4 + reg;
        float s = 0.f;
#pragma unroll
        for (int wi = 0; wi < 8; ++wi) s += sh.lred[wi][lrow];
        linv[rt][reg] = 1.f / s;
      }
  }
  __syncthreads();

  // ---- log-depth acc reduction over 8 waves, per 128-col half ----
#pragma unroll
  for (int hd = 0; hd < 2; ++hd) {
    if (w >= 4) {
#pragma unroll
      for (int rt = 0; rt < 2; ++rt)
#pragma unroll
        for (int i = 0; i < 8; ++i)
#pragma unroll
          for (int reg = 0; reg < 4; ++reg)
            sh.slab[w - 4][(rt * 16 + quad * 4 + reg) * 128 + i * 16 + c] =
                acc[rt][i + 8 * hd][reg];
    }
    __syncthreads();
    if (w < 4) {
#pragma unroll
      for (int rt = 0; rt < 2; ++rt)
#pragma unroll
        for (int i = 0; i < 8; ++i)
#pragma unroll
          for (int reg = 0; reg < 4; ++reg)
            acc[rt][i + 8 * hd][reg] +=
                sh.slab[w][(rt * 16 + quad * 4 + reg) * 128 + i * 16 + c];
    }
    __syncthreads();
    if (w == 2 || w == 3) {
#pragma unroll
      for (int rt = 0; rt < 2; ++rt)
#pragma unroll
        for (int i = 0; i < 8; ++i)
#pragma unroll
          for (int reg = 0; reg < 4; ++reg)
            sh.slab[w - 2][(rt * 16 + quad * 4 + reg) * 128 + i * 16 + c] =
                acc[rt][i + 8 * hd][reg];
    }
    __syncthreads();
    if (w < 2) {
#pragma unroll
      for (int rt = 0; rt < 2; ++rt)
#pragma unroll
        for (int i = 0; i < 8; ++i)
#pragma unroll
          for (int reg = 0; reg < 4; ++reg)
            acc[rt][i + 8 * hd][reg] +=
                sh.slab[w][(rt * 16 + quad * 4 + reg) * 128 + i * 16 + c];
    }
    __syncthreads();
    if (w == 1) {
#pragma unroll
      for (int rt = 0; rt < 2; ++rt)
#pragma unroll
        for (int i = 0; i < 8; ++i)
#pragma unroll
          for (int reg = 0; reg < 4; ++reg)
            sh.slab[0][(rt * 16 + quad * 4 + reg) * 128 + i * 16 + c] =
                acc[rt][i + 8 * hd][reg];
    }
    __syncthreads();
    if (w == 0) {
#pragma unroll
      for (int rt = 0; rt < 2; ++rt)
#pragma unroll
        for (int i = 0; i < 8; ++i)
#pragma unroll
          for (int reg = 0; reg < 4; ++reg) {
            float v = acc[rt][i + 8 * hd][reg] +
                      sh.slab[0][(rt * 16 + quad * 4 + reg) * 128 + i * 16 + c];
            __builtin_nontemporal_store(
                v * linv[rt][reg],
                &out[(size_t)(r0 + rt * 16 + quad * 4 + reg) * DDIM +
                     hd * 128 + i * 16 + c]);
          }
    }
    __syncthreads();
  }
}

extern "C" void kernel_launch(void* const* d_in, const int* in_sizes, int n_in,
                              void* d_out, int out_size, void* d_ws, size_t ws_size,
                              hipStream_t stream) {
  const float* h   = (const float*)d_in[0];
  const int*   adj = (const int*)d_in[1];
  const float* a   = (const float*)d_in[2];
  float* out = (float*)d_out;

  float4*   rc    = (float4*)d_ws;                       // 8192 float4 = 128 KB
  float2*   etab  = (float2*)(rc + NTOT);                // 8192 float2 = 64 KB
  ushort*   hTf   = (ushort*)(etab + NTOT);              // ~4.21 MB bf16 (16B-aligned at 192KB)

  gat_scores<<<NTOT / 4, 256, 0, stream>>>(h, a, rc, etab);
  gat_hpack<<<NTOT / 64, 256, 0, stream>>>(h, hTf);
  gat_attn<<<NTOT / ROWS, 512, 0, stream>>>(hTf, adj, rc, etab, out);
}